// Round 6
// baseline (192.265 us; speedup 1.0000x reference)
//
#include <hip/hip_runtime.h>
#include <hip/hip_bf16.h>

// ---------------------------------------------------------------------------
// CVXPolicy_DoubleIntegrator, R8: TRANSPOSED dataflow — no LDS h round-trip.
//
// R2-R7 post-mortem: all scheduling-level changes (occupancy, stagger,
// setprio, real prefetch) moved <=5%; both resident waves are stalled ~70%
// of the time with all pipes <21% busy. The shared structural feature is the
// per-layer LDS h round-trip (112 scalar ds_writes -> lgkmcnt(0) -> reads)
// on every wave's serial critical path. R8 removes it: compute S^T = W^T X^T
// throughout. The packed weight fragments ALREADY serve as W^T A-operands
// (A-frag lane->[m=l15][k=qd*8+j] reads the same per-lane elements as the
// B-frag layout they were packed for), and the z packing already serves as
// Z^T B-operands — prep and z-loads unchanged. Layer outputs (C: n=batch=l15,
// m=hidden=qd*4+r) convert to the next layer's B-fragments fully in-register:
// cvt_pk_bf16 pairs + fixed qd-permutation shfl (src lane 2*(qd&1)*16+l15 and
// +16) + lane<32 select; kt=3's k in [112,128) garbage is annihilated by the
// zero-padded weight rows. t-fixup is now shuffle-free (t is lane-local),
// QP reduce is 2 shfl_xor, C-write is 12 coalesced dwordx4 stores.
// hbuf (59KB) deleted -> LDS = wbuf 96.25KB + cbl 1.75KB.
//
// Packed weights (bf16, scatter folded into W3, t-row of W1 removed):
//   PW1: frag (kt*7+nt), kt<6, nt<7        -> shorts [0, 21504)
//   PW2: frag 42+kt*7+nt, kt<4, nt<7       -> shorts [21504, 35840)
//   PW3: frag 70+kt*6+nt, kt<4, nt<6       -> shorts [35840, 48128)
//   floats at short-index 48128: w0[112], b1[112], b2[112], bq[96]
// frag = 512 shorts: element e = lane*8+j -> W[k = kt*32+(lane>>4)*8+j][n = nt*16+(lane&15)]
//   (as A-operand this reads W^T[m=nt*16+l15][k] — exactly what R8 needs)
//
// MFMA 16x16x32 bf16 layouts (verified R1):
//   A:   lane -> A[m = lane&15][k = (lane>>4)*8 + j]
//   B:   lane -> B[k = (lane>>4)*8 + j][n = lane&15]
//   C/D: lane -> col = lane&15, row = (lane>>4)*4 + reg
// ---------------------------------------------------------------------------

typedef __attribute__((ext_vector_type(8))) short short8;
typedef __attribute__((ext_vector_type(4))) float f32x4;

__device__ __forceinline__ unsigned short f2bf(float f) {
  unsigned u = __float_as_uint(f);
  u += 0x7fffu + ((u >> 16) & 1u);  // RNE (finite values only)
  return (unsigned short)(u >> 16);
}
__device__ __forceinline__ float tanh_fast(float x) {
  float ax = fabsf(x);
  float e = __builtin_amdgcn_exp2f(ax * -2.88539008177792681f);  // exp(-2ax)
  float r = (1.f - e) * __builtin_amdgcn_rcpf(1.f + e);
  return copysignf(r, x);
}
__device__ __forceinline__ short8 pack_bf8(f32x4 a, f32x4 b) {
  union { short8 s; __hip_bfloat162 h[4]; } u;
  u.h[0] = __float22bfloat162_rn(make_float2(a[0], a[1]));
  u.h[1] = __float22bfloat162_rn(make_float2(a[2], a[3]));
  u.h[2] = __float22bfloat162_rn(make_float2(b[0], b[1]));
  u.h[3] = __float22bfloat162_rn(make_float2(b[2], b[3]));
  return u.s;
}
__device__ __forceinline__ unsigned pk2u(float lo, float hi) {
  union { __hip_bfloat162 h; unsigned u; } x;
  x.h = __float22bfloat162_rn(make_float2(lo, hi));
  return x.u;
}

// ---------------------------------------------------------------------------
// Prep: pack weights bf16, fold scatter into W3, drop t-row (kept as w0 f32).
// (unchanged from R2..R7)
// ---------------------------------------------------------------------------
__global__ void cvx_prep(const float* __restrict__ W1, const float* __restrict__ b1,
                         const float* __restrict__ W2, const float* __restrict__ b2,
                         const float* __restrict__ W3, const float* __restrict__ b3,
                         short* __restrict__ pw) {
  int idx = blockIdx.x * 256 + threadIdx.x;

  if (idx < 21504) {                        // PW1: 6 kt * 7 nt * 512
    int kt = idx / 3584, rem = idx % 3584;
    int nt = rem / 512, e = rem % 512;
    int lane = e >> 3, j = e & 7;
    int k = kt * 32 + (lane >> 4) * 8 + j;  // z index; W1 row k+1
    int n = nt * 16 + (lane & 15);
    float wv = (n < 100) ? W1[(k + 1) * 100 + n] : 0.f;
    pw[(kt * 7 + nt) * 512 + e] = (short)f2bf(wv);
    return;
  }
  idx -= 21504;
  if (idx < 14336) {                        // PW2: 4 kt * 7 nt * 512
    int kt = idx / 3584, rem = idx % 3584;
    int nt = rem / 512, e = rem % 512;
    int lane = e >> 3, j = e & 7;
    int k = kt * 32 + (lane >> 4) * 8 + j;
    int n = nt * 16 + (lane & 15);
    float wv = (k < 100 && n < 100) ? W2[k * 100 + n] : 0.f;
    pw[21504 + (kt * 7 + nt) * 512 + e] = (short)f2bf(wv);
    return;
  }
  idx -= 14336;
  if (idx < 12288) {                        // PW3 folded: 4 kt * 6 nt * 512
    int kt = idx / 3072, rem = idx % 3072;
    int nt = rem / 512, e = rem % 512;
    int lane = e >> 3, j = e & 7;
    int k = kt * 32 + (lane >> 4) * 8 + j;
    int u = nt * 16 + (lane & 15);          // u < 96
    float wv = 0.f;
    if (k < 100) {
      const float* wr = W3 + k * 192;
      if (u <= 31) wv += wr[3 * u + 3];                     // u = i
      if ((u & 1) == 0 && u <= 62) wv += wr[2 * u + 4];     // u = 2i
      if (u % 3 == 0 && u <= 93) wv += wr[(5 * u) / 3 + 5]; // u = 3i
    }
    pw[35840 + (kt * 6 + nt) * 512 + e] = (short)f2bf(wv);
    return;
  }
  idx -= 12288;
  float* cb = (float*)(pw + 48128);
  if (idx < 112) { cb[idx] = (idx < 100) ? W1[idx] : 0.f; return; }        // w0 = W1 row 0
  idx -= 112;
  if (idx < 112) { cb[112 + idx] = (idx < 100) ? b1[idx] : 0.f; return; }
  idx -= 112;
  if (idx < 112) { cb[224 + idx] = (idx < 100) ? b2[idx] : 0.f; return; }
  idx -= 112;
  if (idx < 96) {
    int u = idx;
    float v = 0.f;
    if (u <= 31) v += b3[3 * u + 3];
    if ((u & 1) == 0 && u <= 62) v += b3[2 * u + 4];
    if (u % 3 == 0 && u <= 93) v += b3[(5 * u) / 3 + 5];
    cb[336 + u] = v;
  }
}

// ---------------------------------------------------------------------------
// Main fused kernel: 512 thr (8 waves), 1 block/CU (grid 256), 2 tiles x 256
// rows, 32 rows/wave/tile (2 batch-tiles of 16 = MFMA N dim). Transposed.
// ---------------------------------------------------------------------------
__global__ __launch_bounds__(512, 2) void cvx_main(
    const float* __restrict__ zin, const float* __restrict__ tin,
    const short* __restrict__ pw, float* __restrict__ out) {
  __shared__ __align__(16) short wbuf[48128];  // 96,256 B: all weights
  __shared__ __align__(16) float cbl[448];     // 1,792 B: w0|b1|b2|bq

  const int tid = threadIdx.x;
  const int wid = tid >> 6;
  const int lane = tid & 63;
  const int l15 = lane & 15;
  const int qd = lane >> 4;
  // qd-permutation sources for C->B-frag rebuild:
  const int lo_src = ((lane & 16) << 1) + l15;  // lane of qd'' = 2*(qd&1)
  const int hi_src = lo_src + 16;               // lane of qd'' = 2*(qd&1)+1
  const bool selA = lane < 32;                  // qd<2 -> nt' = 2kt (else 2kt+1)

  // stage ALL weights into LDS (once per block)
  for (int f = wid; f < 94; f += 8) {
    const short* g = pw + f * 512 + lane * 8;
    __builtin_amdgcn_global_load_lds(
        (const __attribute__((address_space(1))) void*)g,
        (__attribute__((address_space(3))) void*)&wbuf[f * 512], 16, 0, 0);
  }
  // stage bias/w0 block into LDS (f32); barrier covers visibility
  if (tid < 448) cbl[tid] = ((const float*)(pw + 48128))[tid];

  const int row0 = blockIdx.x * 512 + wid * 32;

  // tile-0 z,t -> bf16 B-fragments (Z^T), pre-barrier
  short8 XB[2][6];
  float tc0, tc1;
#pragma unroll
  for (int bt = 0; bt < 2; bt++) {
    const float* zr = zin + (size_t)(row0 + bt * 16 + l15) * 192 + qd * 8;
#pragma unroll
    for (int kt = 0; kt < 6; kt++) {
      f32x4 a = *(const f32x4*)(zr + kt * 32);
      f32x4 b = *(const f32x4*)(zr + kt * 32 + 4);
      XB[bt][kt] = pack_bf8(a, b);
    }
  }
  tc0 = tin[row0 + l15];
  tc1 = tin[row0 + 16 + l15];

  __syncthreads();  // the only barrier

  // rebuild one B-fragment of H^T (for K-tile kt) from packed C-layout regs.
  auto buildHB = [&](const unsigned (&pkb)[7][2], int kt) -> short8 {
    union { short8 s; unsigned u[4]; } hb;
    if (kt < 3) {
      unsigned a0 = (unsigned)__shfl((int)pkb[2 * kt][0], lo_src);
      unsigned b0 = (unsigned)__shfl((int)pkb[2 * kt + 1][0], lo_src);
      unsigned a1 = (unsigned)__shfl((int)pkb[2 * kt][1], lo_src);
      unsigned b1_ = (unsigned)__shfl((int)pkb[2 * kt + 1][1], lo_src);
      unsigned a2 = (unsigned)__shfl((int)pkb[2 * kt][0], hi_src);
      unsigned b2_ = (unsigned)__shfl((int)pkb[2 * kt + 1][0], hi_src);
      unsigned a3 = (unsigned)__shfl((int)pkb[2 * kt][1], hi_src);
      unsigned b3_ = (unsigned)__shfl((int)pkb[2 * kt + 1][1], hi_src);
      hb.u[0] = selA ? a0 : b0;
      hb.u[1] = selA ? a1 : b1_;
      hb.u[2] = selA ? a2 : b2_;
      hb.u[3] = selA ? a3 : b3_;
    } else {  // k in [96,112) real (nt'=6); [112,128) garbage x zero-W = safe
      hb.u[0] = (unsigned)__shfl((int)pkb[6][0], lo_src);
      hb.u[1] = (unsigned)__shfl((int)pkb[6][1], lo_src);
      hb.u[2] = (unsigned)__shfl((int)pkb[6][0], hi_src);
      hb.u[3] = (unsigned)__shfl((int)pkb[6][1], hi_src);
    }
    return hb.s;
  };

  short8 XN[2][6];  // next-tile B-fragments (built progressively in tile 0)
  float tn0, tn1;

#pragma unroll 1
  for (int ii = 0; ii < 2; ++ii) {
    const int rb = row0 + ii * 256;

    f32x4 acc[2][7];
#pragma unroll
    for (int nt = 0; nt < 7; nt++) {
      f32x4 zzz = {0.f, 0.f, 0.f, 0.f};
      acc[0][nt] = zzz; acc[1][nt] = zzz;
    }

    // staging regs for one prefetch group: [bt][kt-in-pair][half], 32 f32
    f32x4 sg[2][2][2];
    const float* zb = zin + (size_t)(row0 + 256 + l15) * 192 + qd * 8;

    // ---- issue prefetch group 0 (next-tile kt 0,1) ----
    if (ii == 0) {
#pragma unroll
      for (int bt = 0; bt < 2; bt++)
#pragma unroll
        for (int kp = 0; kp < 2; kp++) {
          sg[bt][kp][0] = *(const f32x4*)(zb + bt * 3072 + kp * 32);
          sg[bt][kp][1] = *(const f32x4*)(zb + bt * 3072 + kp * 32 + 4);
        }
      __builtin_amdgcn_sched_barrier(0);
    }

    // ---- Layer 1 kt = 0,1 :  S1^T = W1^T (A) x Z^T (B) ----
#pragma unroll
    for (int kt = 0; kt < 2; kt++)
#pragma unroll
      for (int nt = 0; nt < 7; nt++) {
        short8 wf = *(const short8*)&wbuf[(kt * 7 + nt) * 512 + lane * 8];
        acc[0][nt] = __builtin_amdgcn_mfma_f32_16x16x32_bf16(wf, XB[0][kt], acc[0][nt], 0, 0, 0);
        acc[1][nt] = __builtin_amdgcn_mfma_f32_16x16x32_bf16(wf, XB[1][kt], acc[1][nt], 0, 0, 0);
      }

    // ---- pack group 0, issue group 1 (kt 2,3) ----
    if (ii == 0) {
#pragma unroll
      for (int bt = 0; bt < 2; bt++)
#pragma unroll
        for (int kp = 0; kp < 2; kp++)
          XN[bt][kp] = pack_bf8(sg[bt][kp][0], sg[bt][kp][1]);
#pragma unroll
      for (int bt = 0; bt < 2; bt++)
#pragma unroll
        for (int kp = 0; kp < 2; kp++) {
          sg[bt][kp][0] = *(const f32x4*)(zb + bt * 3072 + (2 + kp) * 32);
          sg[bt][kp][1] = *(const f32x4*)(zb + bt * 3072 + (2 + kp) * 32 + 4);
        }
      __builtin_amdgcn_sched_barrier(0);
    }

    // ---- Layer 1 kt = 2,3 ----
#pragma unroll
    for (int kt = 2; kt < 4; kt++)
#pragma unroll
      for (int nt = 0; nt < 7; nt++) {
        short8 wf = *(const short8*)&wbuf[(kt * 7 + nt) * 512 + lane * 8];
        acc[0][nt] = __builtin_amdgcn_mfma_f32_16x16x32_bf16(wf, XB[0][kt], acc[0][nt], 0, 0, 0);
        acc[1][nt] = __builtin_amdgcn_mfma_f32_16x16x32_bf16(wf, XB[1][kt], acc[1][nt], 0, 0, 0);
      }

    // ---- pack group 1, issue group 2 (kt 4,5 + t) ----
    if (ii == 0) {
#pragma unroll
      for (int bt = 0; bt < 2; bt++)
#pragma unroll
        for (int kp = 0; kp < 2; kp++)
          XN[bt][2 + kp] = pack_bf8(sg[bt][kp][0], sg[bt][kp][1]);
#pragma unroll
      for (int bt = 0; bt < 2; bt++)
#pragma unroll
        for (int kp = 0; kp < 2; kp++) {
          sg[bt][kp][0] = *(const f32x4*)(zb + bt * 3072 + (4 + kp) * 32);
          sg[bt][kp][1] = *(const f32x4*)(zb + bt * 3072 + (4 + kp) * 32 + 4);
        }
      tn0 = tin[row0 + 256 + l15];
      tn1 = tin[row0 + 256 + 16 + l15];
      __builtin_amdgcn_sched_barrier(0);
    }

    // ---- Layer 1 kt = 4,5 ----
#pragma unroll
    for (int kt = 4; kt < 6; kt++)
#pragma unroll
      for (int nt = 0; nt < 7; nt++) {
        short8 wf = *(const short8*)&wbuf[(kt * 7 + nt) * 512 + lane * 8];
        acc[0][nt] = __builtin_amdgcn_mfma_f32_16x16x32_bf16(wf, XB[0][kt], acc[0][nt], 0, 0, 0);
        acc[1][nt] = __builtin_amdgcn_mfma_f32_16x16x32_bf16(wf, XB[1][kt], acc[1][nt], 0, 0, 0);
      }

    // ---- L1 epilogue: S1^T + t*w0 + b1 -> tanh, all in registers ----
    // lane: batch = l15 (t lane-local), hidden = nt*16 + qd*4 + r
#pragma unroll
    for (int bt = 0; bt < 2; bt++) {
      float tcb = (bt == 0) ? tc0 : tc1;
#pragma unroll
      for (int nt = 0; nt < 7; nt++) {
        f32x4 w0v = *(const f32x4*)&cbl[nt * 16 + qd * 4];
        f32x4 b1v = *(const f32x4*)&cbl[112 + nt * 16 + qd * 4];
#pragma unroll
        for (int r = 0; r < 4; r++)
          acc[bt][nt][r] = tanh_fast(fmaf(tcb, w0v[r], acc[bt][nt][r] + b1v[r]));
      }
    }
    // pack H1^T to bf16 pairs (rp0: r0,r1 ; rp1: r2,r3)
    unsigned pk[2][7][2];
#pragma unroll
    for (int bt = 0; bt < 2; bt++)
#pragma unroll
      for (int nt = 0; nt < 7; nt++) {
        pk[bt][nt][0] = pk2u(acc[bt][nt][0], acc[bt][nt][1]);
        pk[bt][nt][1] = pk2u(acc[bt][nt][2], acc[bt][nt][3]);
      }

    // ---- pack group 2 (loads covered L1 epilogue latency) ----
    if (ii == 0) {
#pragma unroll
      for (int bt = 0; bt < 2; bt++)
#pragma unroll
        for (int kp = 0; kp < 2; kp++)
          XN[bt][4 + kp] = pack_bf8(sg[bt][kp][0], sg[bt][kp][1]);
    }

    // ---- Layer 2: S2^T = W2^T x H1^T (B-frags rebuilt in-register) ----
#pragma unroll
    for (int nt = 0; nt < 7; nt++) {
      f32x4 zzz = {0.f, 0.f, 0.f, 0.f};
      acc[0][nt] = zzz; acc[1][nt] = zzz;
    }
#pragma unroll
    for (int kt = 0; kt < 4; kt++) {
      short8 hb0 = buildHB(pk[0], kt);
      short8 hb1 = buildHB(pk[1], kt);
#pragma unroll
      for (int nt = 0; nt < 7; nt++) {
        short8 wf = *(const short8*)&wbuf[(42 + kt * 7 + nt) * 512 + lane * 8];
        acc[0][nt] = __builtin_amdgcn_mfma_f32_16x16x32_bf16(wf, hb0, acc[0][nt], 0, 0, 0);
        acc[1][nt] = __builtin_amdgcn_mfma_f32_16x16x32_bf16(wf, hb1, acc[1][nt], 0, 0, 0);
      }
    }
    // L2 epilogue: + b2 -> tanh -> repack
#pragma unroll
    for (int bt = 0; bt < 2; bt++)
#pragma unroll
      for (int nt = 0; nt < 7; nt++) {
        f32x4 b2v = *(const f32x4*)&cbl[224 + nt * 16 + qd * 4];
#pragma unroll
        for (int r = 0; r < 4; r++)
          acc[bt][nt][r] = tanh_fast(acc[bt][nt][r] + b2v[r]);
        pk[bt][nt][0] = pk2u(acc[bt][nt][0], acc[bt][nt][1]);
        pk[bt][nt][1] = pk2u(acc[bt][nt][2], acc[bt][nt][3]);
      }

    // ---- Layer 3 (scatter-folded): Q^T = W3f^T x H2^T ----
    f32x4 qa[2][6];
#pragma unroll
    for (int nt = 0; nt < 6; nt++) {
      f32x4 zzz = {0.f, 0.f, 0.f, 0.f};
      qa[0][nt] = zzz; qa[1][nt] = zzz;
    }
#pragma unroll
    for (int kt = 0; kt < 4; kt++) {
      short8 hb0 = buildHB(pk[0], kt);
      short8 hb1 = buildHB(pk[1], kt);
#pragma unroll
      for (int nt = 0; nt < 6; nt++) {
        short8 wf = *(const short8*)&wbuf[(70 + kt * 6 + nt) * 512 + lane * 8];
        qa[0][nt] = __builtin_amdgcn_mfma_f32_16x16x32_bf16(wf, hb0, qa[0][nt], 0, 0, 0);
        qa[1][nt] = __builtin_amdgcn_mfma_f32_16x16x32_bf16(wf, hb1, qa[1][nt], 0, 0, 0);
      }
    }

    // ---- QP epilogue (lane = batch row rb + bt*16 + l15; u = nt*16+qd*4+r) ----
#pragma unroll
    for (int bt = 0; bt < 2; bt++) {
#pragma unroll
      for (int nt = 0; nt < 6; nt++) {
        f32x4 bqv = *(const f32x4*)&cbl[336 + nt * 16 + qd * 4];
        qa[bt][nt] += bqv;
      }
      float loc = 0.f;
#pragma unroll
      for (int nt = 0; nt < 6; nt++) {
        f32x4 q = qa[bt][nt];
        loc += q[0] * q[0] + q[1] * q[1] + q[2] * q[2] + q[3] * q[3];
      }
      loc += __shfl_xor(loc, 16);
      loc += __shfl_xor(loc, 32);     // full ||q||^2 for this row on all 4 qd lanes
      float r2 = loc;
      float s = __builtin_amdgcn_exp2f(__builtin_amdgcn_logf(r2) * 0.333333333333f);
#pragma unroll
      for (int itn = 0; itn < 8; itn++) {
        float one = 1.f + s;
        float fv = fmaf(s * one, one, -r2);
        float fp = one * fmaf(2.f, s, one);
        s = fmaxf(s - fv * __builtin_amdgcn_rcpf(fp), 0.f);
      }
      float inv = -__builtin_amdgcn_rcpf(1.f + s);
      float* orow = out + (size_t)(rb + bt * 16 + l15) * 96;
#pragma unroll
      for (int nt = 0; nt < 6; nt++) {
        f32x4 v = qa[bt][nt] * inv;
        *(f32x4*)(orow + nt * 16 + qd * 4) = v;   // 16 rows x 64B, coalesced
      }
    }

    // ---- rotate next-tile fragments into place ----
    if (ii == 0) {
#pragma unroll
      for (int bt = 0; bt < 2; bt++)
#pragma unroll
        for (int kt = 0; kt < 6; kt++) XB[bt][kt] = XN[bt][kt];
      tc0 = tn0; tc1 = tn1;
    }
  }
}

extern "C" void kernel_launch(void* const* d_in, const int* in_sizes, int n_in,
                              void* d_out, int out_size, void* d_ws, size_t ws_size,
                              hipStream_t stream) {
  const float* z  = (const float*)d_in[0];
  const float* t  = (const float*)d_in[1];
  const float* W1 = (const float*)d_in[2];
  const float* b1 = (const float*)d_in[3];
  const float* W2 = (const float*)d_in[4];
  const float* b2 = (const float*)d_in[5];
  const float* W3 = (const float*)d_in[6];
  const float* b3 = (const float*)d_in[7];
  float* out = (float*)d_out;
  int B = in_sizes[0] / 192;                 // 131072

  short* pw = (short*)d_ws;                  // 97,984 bytes used
  cvx_prep<<<190, 256, 0, stream>>>(W1, b1, W2, b2, W3, b3, pw);
  cvx_main<<<B / 512, 512, 0, stream>>>(z, t, pw, out);
}